// Round 7
// baseline (528.193 us; speedup 1.0000x reference)
//
#include <hip/hip_runtime.h>

#define BATCH 512
#define SEQ   512
#define IN    28
#define HID   128
#define NCLS  10
#define ROWS  2
#define PAD20(k) (((k) >> 4) * 20 + ((k) & 15))   // 16-float slice padded to 20 (R4/R6-verified conflict-free)

__device__ __forceinline__ float fast_tanh(float x) {
    float e = __expf(2.0f * x);
    return 1.0f - 2.0f * __builtin_amdgcn_rcpf(e + 1.0f);
}

template<int CTRL>
__device__ __forceinline__ float dpp_add(float v) {
    int n = __builtin_amdgcn_update_dpp(0, __float_as_int(v), CTRL, 0xF, 0xF, true);
    return v + __int_as_float(n);
}
// 8-lane reduce; valid in lane sl==0 of each 8-group (R4/R6-verified).
__device__ __forceinline__ float reduce8(float v) {
    v = dpp_add<0xB1>(v);     // quad_perm xor1
    v = dpp_add<0x4E>(v);     // quad_perm xor2
    v = dpp_add<0x12C>(v);    // row_ror:12 -> lane i += lane (i+4)&15
    return v;
}

__global__ __launch_bounds__(512, 2)
void rnn2_kernel(const float* __restrict__ x,
                 const float* __restrict__ W_ih0, const float* __restrict__ W_hh0,
                 const float* __restrict__ b_ih0, const float* __restrict__ b_hh0,
                 const float* __restrict__ W_ih1, const float* __restrict__ W_hh1,
                 const float* __restrict__ b_ih1, const float* __restrict__ b_hh1,
                 const float* __restrict__ W_fc,  const float* __restrict__ b_fc,
                 float* __restrict__ out)
{
    __shared__ __align__(16) float h0buf[2][ROWS][8 * 20];
    __shared__ __align__(16) float h1buf[2][ROWS][8 * 20];

    const int t  = threadIdx.x;      // 0..511
    const int g  = t >> 3;           // unit-group 0..63 -> units 2g, 2g+1
    const int sl = t & 7;            // k-slice 0..7 (16 k each)
    const int j0 = 2 * g;
    const int hk = 16 * sl;

    // ---- weights: 2 units x (4 ih0 + 16 hh0 + 16 ih1 + 16 hh1) = 104 floats/thread
    float wih0[2][4], whh0[2][16], wih1[2][16], whh1[2][16];
    #pragma unroll
    for (int u = 0; u < 2; ++u) {
        if (sl < 7) {
            const float* p = W_ih0 + (j0 + u) * IN + sl * 4;
            #pragma unroll
            for (int k = 0; k < 4; ++k) wih0[u][k] = p[k];
        } else {
            #pragma unroll
            for (int k = 0; k < 4; ++k) wih0[u][k] = 0.0f;
        }
        const float* p0 = W_hh0 + (j0 + u) * HID + hk;
        const float* p1 = W_ih1 + (j0 + u) * HID + hk;
        const float* p2 = W_hh1 + (j0 + u) * HID + hk;
        #pragma unroll
        for (int k = 0; k < 16; ++k) {
            whh0[u][k] = p0[k];
            wih1[u][k] = p1[k];
            whh1[u][k] = p2[k];
        }
    }
    const float bias0_0 = b_ih0[j0] + b_hh0[j0];
    const float bias0_1 = b_ih0[j0 + 1] + b_hh0[j0 + 1];
    const float bias1_0 = b_ih1[j0] + b_hh1[j0];
    const float bias1_1 = b_ih1[j0 + 1] + b_hh1[j0 + 1];

    if (t < 8 * 20) {
        #pragma unroll
        for (int r = 0; r < ROWS; ++r) {
            h0buf[0][r][t] = 0.0f;
            h1buf[0][r][t] = 0.0f;
        }
    }

    // ---- x: direct global reads, prefetched one iteration ahead
    const int xoff = (sl < 7) ? sl * 4 : 0;      // sl==7 has zero x-weights; clamp in-bounds
    const float* xrow[ROWS];
    float4 xcur[ROWS];
    #pragma unroll
    for (int r = 0; r < ROWS; ++r) {
        xrow[r] = x + ((size_t)(blockIdx.x * ROWS + r) * SEQ) * IN + xoff;
        xcur[r] = *(const float4*)(xrow[r]);     // x(0)
    }

    __syncthreads();

    const int ws0 = PAD20(j0);   // units 2g,2g+1 are adjacent in the same 16-chunk (j0 even)

    // ---- pipelined time loop (R6 structure): iteration it computes h0(it) AND h1(it-1).
    for (int it = 0; it <= SEQ; ++it) {
        const int rd = it & 1, wr = rd ^ 1;
        const int nxtoff = ((it < SEQ - 1) ? (it + 1) : (SEQ - 1)) * IN;

        float redA[ROWS][2], redB[ROWS][2];
        #pragma unroll
        for (int r = 0; r < ROWS; ++r) {
            float4 xn = *(const float4*)(xrow[r] + nxtoff);   // prefetch x(it+1)

            const float4* h0p = (const float4*)&h0buf[rd][r][sl * 20];
            const float4* h1p = (const float4*)&h1buf[rd][r][sl * 20];
            float4 p0 = h0p[0], p1 = h0p[1], p2 = h0p[2], p3 = h0p[3];
            float4 q0 = h1p[0], q1 = h1p[1], q2 = h1p[2], q3 = h1p[3];

            #pragma unroll
            for (int u = 0; u < 2; ++u) {
                // A-chain: Wih0·x + Whh0·h0_prev
                float a0 = wih0[u][0] * xcur[r].x;
                float a1 = wih0[u][1] * xcur[r].y;
                float a2 = wih0[u][2] * xcur[r].z;
                float a3 = wih0[u][3] * xcur[r].w;
                a0 = fmaf(whh0[u][ 0], p0.x, a0); a1 = fmaf(whh0[u][ 1], p0.y, a1);
                a2 = fmaf(whh0[u][ 2], p0.z, a2); a3 = fmaf(whh0[u][ 3], p0.w, a3);
                a0 = fmaf(whh0[u][ 4], p1.x, a0); a1 = fmaf(whh0[u][ 5], p1.y, a1);
                a2 = fmaf(whh0[u][ 6], p1.z, a2); a3 = fmaf(whh0[u][ 7], p1.w, a3);
                a0 = fmaf(whh0[u][ 8], p2.x, a0); a1 = fmaf(whh0[u][ 9], p2.y, a1);
                a2 = fmaf(whh0[u][10], p2.z, a2); a3 = fmaf(whh0[u][11], p2.w, a3);
                a0 = fmaf(whh0[u][12], p3.x, a0); a1 = fmaf(whh0[u][13], p3.y, a1);
                a2 = fmaf(whh0[u][14], p3.z, a2); a3 = fmaf(whh0[u][15], p3.w, a3);

                // B-chain: Wih1·h0_prev + Whh1·h1_prev2
                float c0 = wih1[u][0] * p0.x;
                float c1 = wih1[u][1] * p0.y;
                float c2 = wih1[u][2] * p0.z;
                float c3 = wih1[u][3] * p0.w;
                c0 = fmaf(wih1[u][ 4], p1.x, c0); c1 = fmaf(wih1[u][ 5], p1.y, c1);
                c2 = fmaf(wih1[u][ 6], p1.z, c2); c3 = fmaf(wih1[u][ 7], p1.w, c3);
                c0 = fmaf(wih1[u][ 8], p2.x, c0); c1 = fmaf(wih1[u][ 9], p2.y, c1);
                c2 = fmaf(wih1[u][10], p2.z, c2); c3 = fmaf(wih1[u][11], p2.w, c3);
                c0 = fmaf(wih1[u][12], p3.x, c0); c1 = fmaf(wih1[u][13], p3.y, c1);
                c2 = fmaf(wih1[u][14], p3.z, c2); c3 = fmaf(wih1[u][15], p3.w, c3);
                c0 = fmaf(whh1[u][ 0], q0.x, c0); c1 = fmaf(whh1[u][ 1], q0.y, c1);
                c2 = fmaf(whh1[u][ 2], q0.z, c2); c3 = fmaf(whh1[u][ 3], q0.w, c3);
                c0 = fmaf(whh1[u][ 4], q1.x, c0); c1 = fmaf(whh1[u][ 5], q1.y, c1);
                c2 = fmaf(whh1[u][ 6], q1.z, c2); c3 = fmaf(whh1[u][ 7], q1.w, c3);
                c0 = fmaf(whh1[u][ 8], q2.x, c0); c1 = fmaf(whh1[u][ 9], q2.y, c1);
                c2 = fmaf(whh1[u][10], q2.z, c2); c3 = fmaf(whh1[u][11], q2.w, c3);
                c0 = fmaf(whh1[u][12], q3.x, c0); c1 = fmaf(whh1[u][13], q3.y, c1);
                c2 = fmaf(whh1[u][14], q3.z, c2); c3 = fmaf(whh1[u][15], q3.w, c3);

                redA[r][u] = reduce8((a0 + a2) + (a1 + a3));
                redB[r][u] = reduce8((c0 + c2) + (c1 + c3));
            }
            xcur[r] = xn;
        }

        if (sl == 0) {
            #pragma unroll
            for (int r = 0; r < ROWS; ++r) {
                float2 hv0;
                hv0.x = fast_tanh(redA[r][0] + bias0_0);
                hv0.y = fast_tanh(redA[r][1] + bias0_1);
                *(float2*)&h0buf[wr][r][ws0] = hv0;
                float2 hv1;
                if (it == 0) {
                    hv1.x = 0.0f; hv1.y = 0.0f;
                } else {
                    hv1.x = fast_tanh(redB[r][0] + bias1_0);
                    hv1.y = fast_tanh(redB[r][1] + bias1_1);
                }
                *(float2*)&h1buf[wr][r][ws0] = hv1;
            }
        }
        __syncthreads();
    }

    // ---- fc epilogue: it=SEQ wrote h1(511) into buffer wr = (SEQ&1)^1 = 1
    if (t < ROWS * NCLS) {
        const int r = t / NCLS, c = t % NCLS;
        float acc = b_fc[c];
        const float* wf = W_fc + c * HID;
        #pragma unroll 4
        for (int k = 0; k < HID; ++k)
            acc = fmaf(wf[k], h1buf[1][r][PAD20(k)], acc);
        out[(blockIdx.x * ROWS + r) * NCLS + c] = acc;
    }
}

extern "C" void kernel_launch(void* const* d_in, const int* in_sizes, int n_in,
                              void* d_out, int out_size, void* d_ws, size_t ws_size,
                              hipStream_t stream) {
    const float* x     = (const float*)d_in[0];
    const float* W_ih0 = (const float*)d_in[1];
    const float* W_hh0 = (const float*)d_in[2];
    const float* b_ih0 = (const float*)d_in[3];
    const float* b_hh0 = (const float*)d_in[4];
    const float* W_ih1 = (const float*)d_in[5];
    const float* W_hh1 = (const float*)d_in[6];
    const float* b_ih1 = (const float*)d_in[7];
    const float* b_hh1 = (const float*)d_in[8];
    const float* W_fc  = (const float*)d_in[9];
    const float* b_fc  = (const float*)d_in[10];
    float* out = (float*)d_out;

    rnn2_kernel<<<dim3(BATCH / ROWS), dim3(512), 0, stream>>>(
        x, W_ih0, W_hh0, b_ih0, b_hh0, W_ih1, W_hh1, b_ih1, b_hh1, W_fc, b_fc, out);
}